// Round 1
// baseline (978.993 us; speedup 1.0000x reference)
//
#include <hip/hip_runtime.h>
#include <hip/hip_bf16.h>
#include <cstddef>

// Problem constants
constexpr int B_  = 2;
constexpr int T_  = 8;
constexpr int HW_ = 37;          // H == W == 37
constexpr int N_  = HW_ * HW_;   // 1369
constexpr int C_  = 384;
constexpr int NH_ = 8;
constexpr int MP_ = 8;
constexpr int HD_ = C_ / NH_;    // 48
constexpr int M_  = B_ * T_ * N_; // 21904

// ---------------------------------------------------------------------------
// Generic fp32 GEMM + bias: out[M,N] = A[M,K] @ W[K,N] + bias[N]
// Tiles: BM=64, BN=64, BK=16; 256 threads; 4x4 per thread.
// ---------------------------------------------------------------------------
#define BMg 64
#define BNg 64
#define BKg 16

__global__ __launch_bounds__(256)
void gemm_bias_kernel(const float* __restrict__ A, const float* __restrict__ W,
                      const float* __restrict__ bias, float* __restrict__ out,
                      int M, int N, int K) {
  __shared__ float As[BKg][BMg + 4];
  __shared__ float Bs[BKg][BNg + 4];
  const int tid = threadIdx.x;
  const int tx = tid & 15;
  const int ty = tid >> 4;
  const int block_m = blockIdx.x * BMg;
  const int block_n = blockIdx.y * BNg;
  float acc[4][4] = {};

  for (int k0 = 0; k0 < K; k0 += BKg) {
    // A tile: 64x16 elems; consecutive threads read consecutive k (coalesced 64B groups)
#pragma unroll
    for (int i = 0; i < 4; ++i) {
      int e = tid + i * 256;
      int m = e >> 4;
      int kk = e & 15;
      int gm = block_m + m;
      As[kk][m] = (gm < M) ? A[(size_t)gm * K + (k0 + kk)] : 0.f;
    }
    // W tile: 16x64
#pragma unroll
    for (int i = 0; i < 4; ++i) {
      int e = tid + i * 256;
      int kk = e >> 6;
      int nn = e & 63;
      Bs[kk][nn] = W[(size_t)(k0 + kk) * N + block_n + nn];
    }
    __syncthreads();
#pragma unroll
    for (int kk = 0; kk < BKg; ++kk) {
      float4 a4 = *(const float4*)&As[kk][ty * 4];
      float4 b4 = *(const float4*)&Bs[kk][tx * 4];
      float a[4] = {a4.x, a4.y, a4.z, a4.w};
      float b[4] = {b4.x, b4.y, b4.z, b4.w};
#pragma unroll
      for (int i = 0; i < 4; ++i)
#pragma unroll
        for (int j = 0; j < 4; ++j)
          acc[i][j] += a[i] * b[j];
    }
    __syncthreads();
  }

#pragma unroll
  for (int i = 0; i < 4; ++i) {
    int gm = block_m + ty * 4 + i;
    if (gm >= M) continue;
#pragma unroll
    for (int j = 0; j < 4; ++j) {
      int gn = block_n + tx * 4 + j;
      out[(size_t)gm * N + gn] = acc[i][j] + bias[gn];
    }
  }
}

// ---------------------------------------------------------------------------
// Deformable attention core.
// One block per (b, t, n); 4 waves; each wave handles 2 heads sequentially.
// Per head:
//   phase 1: lanes 0..47 = hd; gather bilinear samples of all T ref frames at
//            the 8 predicted points into LDS s[r][p][49] (padded, conflict-free)
//   phase 2: lane = (r,p); logit = q . s (48 LDS reads), mask, 8-lane softmax
//   phase 3: lanes 0..47 = hd; out[hd] = sum_{r,p} attn * s, * 1/T
// ---------------------------------------------------------------------------
__global__ __launch_bounds__(256)
void attend_kernel(const float* __restrict__ f, const float* __restrict__ Q,
                   const float* __restrict__ OFF, float* __restrict__ O1) {
  __shared__ float s_lds[4][T_][MP_][49];
  __shared__ float q_lds[4][HD_];
  __shared__ float attn_lds[4][64];

  const int blk = blockIdx.x;        // (b*T + t)*N + n
  const int n   = blk % N_;
  const int bt  = blk / N_;          // b*T + t
  const int t   = bt % T_;
  const int b   = bt / T_;
  const int wave = threadIdx.x >> 6;
  const int lane = threadIdx.x & 63;
  const float cy = (float)(n / HW_);
  const float cx = (float)(n % HW_);
  const size_t row = (size_t)bt * N_ + n;

  for (int hi = 0; hi < 2; ++hi) {
    const int h = wave * 2 + hi;
    __syncthreads();   // protect s_lds reuse across head iterations
    if (lane < HD_) q_lds[wave][lane] = Q[row * C_ + h * HD_ + lane];

    // ---- phase 1: gather ----
    const float* offp = OFF + row * (NH_ * MP_ * 2) + h * (MP_ * 2);
    for (int p = 0; p < MP_; ++p) {
      float y = cy + offp[p * 2 + 0];
      float x = cx + offp[p * 2 + 1];
      float y0f = floorf(y), x0f = floorf(x);
      float wy = y - y0f, wx = x - x0f;
      int y0 = (int)y0f, x0 = (int)x0f;
      int y1 = y0 + 1, x1 = x0 + 1;
      float vy0 = (y0 >= 0 && y0 < HW_) ? 1.f : 0.f;
      float vy1 = (y1 >= 0 && y1 < HW_) ? 1.f : 0.f;
      float vx0 = (x0 >= 0 && x0 < HW_) ? 1.f : 0.f;
      float vx1 = (x1 >= 0 && x1 < HW_) ? 1.f : 0.f;
      int cy0 = min(max(y0, 0), HW_ - 1), cy1 = min(max(y1, 0), HW_ - 1);
      int cx0 = min(max(x0, 0), HW_ - 1), cx1 = min(max(x1, 0), HW_ - 1);
      float w00 = (1.f - wy) * (1.f - wx) * vy0 * vx0;
      float w01 = (1.f - wy) * wx * vy0 * vx1;
      float w10 = wy * (1.f - wx) * vy1 * vx0;
      float w11 = wy * wx * vy1 * vx1;
      int i00 = cy0 * HW_ + cx0, i01 = cy0 * HW_ + cx1;
      int i10 = cy1 * HW_ + cx0, i11 = cy1 * HW_ + cx1;
      if (lane < HD_) {
        const int ch = h * HD_ + lane;
#pragma unroll
        for (int r = 0; r < T_; ++r) {
          const float* fr = f + ((size_t)(b * T_ + r) * N_) * C_ + ch;
          float s = w00 * fr[(size_t)i00 * C_] + w01 * fr[(size_t)i01 * C_]
                  + w10 * fr[(size_t)i10 * C_] + w11 * fr[(size_t)i11 * C_];
          s_lds[wave][r][p][lane] = s;
        }
      }
    }
    __syncthreads();

    // ---- phase 2: logits + masked softmax over p ----
    {
      const int r = lane >> 3, p = lane & 7;
      float logit = 0.f;
#pragma unroll
      for (int d = 0; d < HD_; ++d)
        logit += q_lds[wave][d] * s_lds[wave][r][p][d];
      logit *= 0.144337567297406441f;  // 1/sqrt(48)
      int dd = t - r; if (dd < 0) dd = -dd;
      int npts = (56 - 8 * dd) / 7; if (npts < 1) npts = 1;
      if (p >= npts) logit = -1e30f;
      float m = logit;
#pragma unroll
      for (int s = 1; s < 8; s <<= 1) m = fmaxf(m, __shfl_xor(m, s, 8));
      float e = __expf(logit - m);
      float sum = e;
#pragma unroll
      for (int s = 1; s < 8; s <<= 1) sum += __shfl_xor(sum, s, 8);
      attn_lds[wave][lane] = e / sum * 0.125f;   // fold 1/T mean
    }
    __syncthreads();

    // ---- phase 3: weighted accumulate ----
    if (lane < HD_) {
      float acc = 0.f;
#pragma unroll
      for (int rp = 0; rp < 64; ++rp)
        acc += attn_lds[wave][rp] * s_lds[wave][rp >> 3][rp & 7][lane];
      O1[row * C_ + h * HD_ + lane] = acc;
    }
  }
}

// ---------------------------------------------------------------------------
extern "C" void kernel_launch(void* const* d_in, const int* in_sizes, int n_in,
                              void* d_out, int out_size, void* d_ws, size_t ws_size,
                              hipStream_t stream) {
  const float* f    = (const float*)d_in[0];
  const float* Wq   = (const float*)d_in[1];
  const float* bq   = (const float*)d_in[2];
  const float* Woff = (const float*)d_in[3];
  const float* boff = (const float*)d_in[4];
  const float* Wout = (const float*)d_in[5];
  const float* bout = (const float*)d_in[6];
  float* outp = (float*)d_out;

  float* Qbuf = (float*)d_ws;                          // [M, 384]
  float* OFFb = Qbuf + (size_t)M_ * C_;                // [M, 128]
  float* O1   = OFFb + (size_t)M_ * (NH_ * MP_ * 2);   // [M, 384]

  dim3 blk(256);
  dim3 gq((M_ + BMg - 1) / BMg, C_ / BNg);             // 343 x 6
  gemm_bias_kernel<<<gq, blk, 0, stream>>>(f, Wq, bq, Qbuf, M_, C_, C_);

  dim3 go((M_ + BMg - 1) / BMg, (NH_ * MP_ * 2) / BNg); // 343 x 2
  gemm_bias_kernel<<<go, blk, 0, stream>>>(f, Woff, boff, OFFb, M_, NH_ * MP_ * 2, C_);

  attend_kernel<<<dim3(M_), blk, 0, stream>>>(f, Qbuf, OFFb, O1);

  gemm_bias_kernel<<<gq, blk, 0, stream>>>(O1, Wout, bout, outp, M_, C_, C_);
}